// Round 1
// baseline (25387.215 us; speedup 1.0000x reference)
//
#include <hip/hip_runtime.h>

// Problem constants (B=32, C=128, H=72, W=200, K=9, PAD=4)
#define CC  128
#define HH  72
#define WW  200
#define HW_ (HH*WW)        // 14400
#define CHW (CC*HW_)       // 1843200
#define WREP_FLOATS (CC*CC*12)   // 196608 floats = 786432 B per tensor

// ---------------------------------------------------------------------------
// Repack w[c][ci][9] -> wq[(ci*3+kk)*128 + c] as float4 (k padded 9->12, zeros)
// Coalesced: adjacent c -> adjacent float4.
// Grid (64, 4), block 256. blockIdx.y selects tensor {d,u,r,l}.
// ---------------------------------------------------------------------------
__global__ __launch_bounds__(256) void repack_kern(
    const float* __restrict__ w0, const float* __restrict__ w1,
    const float* __restrict__ w2, const float* __restrict__ w3,
    float* __restrict__ outp)
{
    const float* src = (blockIdx.y == 0) ? w0 : (blockIdx.y == 1) ? w1
                     : (blockIdx.y == 2) ? w2 : w3;
    float* dst = outp + (size_t)blockIdx.y * WREP_FLOATS;
    int idx = blockIdx.x * 256 + threadIdx.x;   // 16384 = (c, ci)
    int c  = idx >> 7;
    int ci = idx & 127;
    const float* wp = src + ((size_t)c * CC + ci) * 9;
    float v[12];
    #pragma unroll
    for (int k = 0; k < 9; k++) v[k] = wp[k];
    v[9] = v[10] = v[11] = 0.f;
    float4* o = (float4*)dst;
    #pragma unroll
    for (int kk = 0; kk < 3; kk++)
        o[(ci * 3 + kk) * CC + c] = make_float4(v[kk*4], v[kk*4+1], v[kk*4+2], v[kk*4+3]);
}

// ---------------------------------------------------------------------------
// Sweep step v2: software-pipelined ci loop, coalesced padded weights.
// State (B, C, R, L), L contiguous; recurrence walks R:
//   st[b][c][r_dst][l] += relu(bias[c] + sum_{ci,k} w[c][ci][k]*st[b][ci][r_src][l+k-4])
// Block: 128 threads = 32 c_out (cgrp=t&31) x 4 l-groups (lgrp=t>>5) of LPT l.
// Tile: 32 c_out x (4*LPT) l for one b. LDS: prev row window (all 128 ci).
// Row reads: 2 distinct addrs/wave (broadcast, conflict-free).
// Weight reads: 3 coalesced dwordx4/iter, prefetched 1 iter ahead.
// ---------------------------------------------------------------------------
template<int L, int LPT>
__global__ __launch_bounds__(128) void step2_kern(
    float* __restrict__ st, const float* __restrict__ wq,
    const float* __restrict__ bias, int r_src, int r_dst)
{
    constexpr int TL  = 4 * LPT;
    constexpr int WIN = TL + 8;
    __shared__ __align__(16) float lds[CC * WIN];
    const int b     = blockIdx.z;
    const int lbase = blockIdx.x * TL;
    const int cbase = blockIdx.y * 32;
    const int t     = threadIdx.x;

    const float* src = st + (size_t)b * CHW + (size_t)r_src * L;
    #pragma unroll
    for (int i2 = 0; i2 < (CC * WIN) / 128; i2++) {
        int i  = t + i2 * 128;
        int ci = i / WIN;
        int lo = i - ci * WIN;
        int l  = lbase - 4 + lo;
        lds[i] = (l >= 0 && l < L) ? src[(size_t)ci * HW_ + l] : 0.f;
    }
    __syncthreads();

    const int cgrp = t & 31;
    const int lgrp = t >> 5;
    const int c    = cbase + cgrp;
    const int l0   = lbase + lgrp * LPT;

    const float4* wq4 = (const float4*)wq;
    float acc[LPT] = {};
    float p[LPT + 8];
    float4 w0, w1, w2;
    {
        const float* lp = &lds[lgrp * LPT];           // ci = 0
        #pragma unroll
        for (int j = 0; j < LPT + 8; j++) p[j] = lp[j];
        w0 = wq4[0 * CC + c];
        w1 = wq4[1 * CC + c];
        w2 = wq4[2 * CC + c];
    }

    for (int ci = 0; ci < CC - 1; ci++) {
        // prefetch ci+1 (weights from L2, rows from LDS) while FMAing ci
        float4 nw0 = wq4[((ci + 1) * 3 + 0) * CC + c];
        float4 nw1 = wq4[((ci + 1) * 3 + 1) * CC + c];
        float4 nw2 = wq4[((ci + 1) * 3 + 2) * CC + c];
        float np[LPT + 8];
        const float* lp = &lds[(ci + 1) * WIN + lgrp * LPT];
        #pragma unroll
        for (int j = 0; j < LPT + 8; j++) np[j] = lp[j];

        const float wk[9] = {w0.x, w0.y, w0.z, w0.w, w1.x, w1.y, w1.z, w1.w, w2.x};
        #pragma unroll
        for (int k = 0; k < 9; k++)
            #pragma unroll
            for (int j = 0; j < LPT; j++)
                acc[j] = fmaf(wk[k], p[j + k], acc[j]);

        #pragma unroll
        for (int j = 0; j < LPT + 8; j++) p[j] = np[j];
        w0 = nw0; w1 = nw1; w2 = nw2;
    }
    {   // ci = 127 epilogue
        const float wk[9] = {w0.x, w0.y, w0.z, w0.w, w1.x, w1.y, w1.z, w1.w, w2.x};
        #pragma unroll
        for (int k = 0; k < 9; k++)
            #pragma unroll
            for (int j = 0; j < LPT; j++)
                acc[j] = fmaf(wk[k], p[j + k], acc[j]);
    }

    if (l0 < L) {   // tiles are exact multiples of LPT; guard is whole-thread
        const float bb = bias[c];
        float* po = st + (size_t)b * CHW + (size_t)c * HW_ + (size_t)r_dst * L + l0;
        #pragma unroll
        for (int j = 0; j < LPT; j++)
            po[j] += fmaxf(acc[j] + bb, 0.f);
    }
}

// ---------------------------------------------------------------------------
// Old round-2 step kernel — kept as fallback when ws has no room for wrep.
// ---------------------------------------------------------------------------
template<int L>
__global__ __launch_bounds__(256) void step_kern(
    float* __restrict__ st, const float* __restrict__ wgt,
    const float* __restrict__ bias, int r_src, int r_dst)
{
    __shared__ float lds[CC * 40];
    const int b     = blockIdx.z;
    const int lbase = blockIdx.x * 32;
    const int cbase = blockIdx.y * 64;
    const int t     = threadIdx.x;

    const float* src = st + (size_t)b * CHW + (size_t)r_src * L;
    #pragma unroll
    for (int i = 0; i < 20; i++) {
        int idx = t + i * 256;
        int ci  = idx / 40;
        int lo  = idx - ci * 40;
        int l   = lbase - 4 + lo;
        lds[idx] = (l >= 0 && l < L) ? src[(size_t)ci * HW_ + l] : 0.f;
    }
    __syncthreads();

    const int lgrp = t & 7;
    const int cgrp = t >> 3;
    const int l0   = lbase + lgrp * 4;
    const int c0   = cbase + cgrp * 2;

    float acc[2][4] = {};
    for (int ci = 0; ci < CC; ci++) {
        float p[12];
        const float* lp = &lds[ci * 40 + lgrp * 4];
        #pragma unroll
        for (int j = 0; j < 12; j++) p[j] = lp[j];
        #pragma unroll
        for (int c = 0; c < 2; c++) {
            const float* wp = wgt + ((size_t)(c0 + c) * CC + ci) * 9;
            #pragma unroll
            for (int k = 0; k < 9; k++) {
                const float wv = wp[k];
                #pragma unroll
                for (int j = 0; j < 4; j++)
                    acc[c][j] = fmaf(wv, p[j + k], acc[c][j]);
            }
        }
    }

    if (l0 < L) {
        #pragma unroll
        for (int c = 0; c < 2; c++) {
            float* po = st + (size_t)b * CHW + (size_t)(c0 + c) * HW_
                           + (size_t)r_dst * L + l0;
            float4 v = *(float4*)po;
            const float bb = bias[c0 + c];
            v.x += fmaxf(acc[c][0] + bb, 0.f);
            v.y += fmaxf(acc[c][1] + bb, 0.f);
            v.z += fmaxf(acc[c][2] + bb, 0.f);
            v.w += fmaxf(acc[c][3] + bb, 0.f);
            *(float4*)po = v;
        }
    }
}

// ---------------------------------------------------------------------------
// Per-plane 2D transpose: in (rows x cols) -> out (cols x rows), z = B*C planes.
// ---------------------------------------------------------------------------
__global__ __launch_bounds__(256) void transpose_kern(
    const float* __restrict__ in, float* __restrict__ outp, int rows, int cols)
{
    __shared__ float tile[32][33];
    const size_t plane = (size_t)rows * cols;
    const float* ip = in   + (size_t)blockIdx.z * plane;
    float*       op = outp + (size_t)blockIdx.z * plane;
    const int c0 = blockIdx.x * 32, r0 = blockIdx.y * 32;
    const int tx = threadIdx.x, ty = threadIdx.y;

    #pragma unroll
    for (int i = 0; i < 32; i += 8) {
        int r = r0 + ty + i, c = c0 + tx;
        if (r < rows && c < cols) tile[ty + i][tx] = ip[(size_t)r * cols + c];
    }
    __syncthreads();
    #pragma unroll
    for (int i = 0; i < 32; i += 8) {
        int r = c0 + ty + i, c = r0 + tx;
        if (r < cols && c < rows) op[(size_t)r * rows + c] = tile[tx][ty + i];
    }
}

// ---------------------------------------------------------------------------
// Round-1 strided column-step kernel: last-resort fallback (tiny ws).
// ---------------------------------------------------------------------------
__global__ __launch_bounds__(256) void stepH_kern(
    float* __restrict__ out, const float* __restrict__ wgt,
    const float* __restrict__ bias, int w_src, int w_dst)
{
    __shared__ float lds[CC * 32];
    const int b     = blockIdx.z;
    const int hbase = blockIdx.x * 24;
    const int cbase = blockIdx.y * 32;
    const int t     = threadIdx.x;

    const float* srcb = out + (size_t)b * CHW + w_src;
    for (int i = t; i < CC * 32; i += 256) {
        int ci = i >> 5;
        int ho = i & 31;
        int h  = hbase - 4 + ho;
        lds[i] = (h >= 0 && h < HH) ? srcb[(size_t)ci * HW_ + (size_t)h * WW] : 0.f;
    }
    __syncthreads();

    const int hgrp  = t & 7;
    const int cgrp  = t >> 3;
    const int h0    = hgrp * 3;
    const int c_out = cbase + cgrp;

    float acc[3] = {};
    for (int ci = 0; ci < CC; ci++) {
        float p[11];
        const float* lp = &lds[ci * 32 + h0];
        #pragma unroll
        for (int j = 0; j < 11; j++) p[j] = lp[j];
        const float* wp = wgt + ((size_t)c_out * CC + ci) * 9;
        #pragma unroll
        for (int k = 0; k < 9; k++) {
            const float wv = wp[k];
            #pragma unroll
            for (int m = 0; m < 3; m++)
                acc[m] = fmaf(wv, p[m + k], acc[m]);
        }
    }

    const float bb = bias[c_out];
    float* po = out + (size_t)b * CHW + (size_t)c_out * HW_
                    + (size_t)(hbase + h0) * WW + w_dst;
    #pragma unroll
    for (int m = 0; m < 3; m++)
        po[(size_t)m * WW] += fmaxf(acc[m] + bb, 0.f);
}

// ---------------------------------------------------------------------------
extern "C" void kernel_launch(void* const* d_in, const int* in_sizes, int n_in,
                              void* d_out, int out_size, void* d_ws, size_t ws_size,
                              hipStream_t stream)
{
    const float* x   = (const float*)d_in[0];
    const float* w_d = (const float*)d_in[1];
    const float* b_d = (const float*)d_in[2];
    const float* w_u = (const float*)d_in[3];
    const float* b_u = (const float*)d_in[4];
    const float* w_r = (const float*)d_in[5];
    const float* b_r = (const float*)d_in[6];
    const float* w_l = (const float*)d_in[7];
    const float* b_l = (const float*)d_in[8];
    float* out = (float*)d_out;
    float* ws  = (float*)d_ws;

    const size_t bytes      = (size_t)32 * CHW * sizeof(float);
    const size_t wrep_bytes = (size_t)4 * WREP_FLOATS * sizeof(float);
    hipMemcpyAsync(out, x, bytes, hipMemcpyDeviceToDevice, stream);

    if (ws_size >= bytes + wrep_bytes) {
        // ---------------- new path: pipelined kernels + repacked weights ----
        float* wrep = (float*)((char*)d_ws + bytes);
        repack_kern<<<dim3(64, 4), 256, 0, stream>>>(w_d, w_u, w_r, w_l, wrep);
        const float* q_d = wrep + 0 * (size_t)WREP_FLOATS;
        const float* q_u = wrep + 1 * (size_t)WREP_FLOATS;
        const float* q_r = wrep + 2 * (size_t)WREP_FLOATS;
        const float* q_l = wrep + 3 * (size_t)WREP_FLOATS;

        const dim3 blk(128);
        const dim3 gW(7, 4, 32);    // 896 blocks: 32c x 32l tiles
        for (int h = 1; h < HH; h++)
            step2_kern<WW, 8><<<gW, blk, 0, stream>>>(out, q_d, b_d, h - 1, h);
        for (int h = HH - 2; h >= 0; h--)
            step2_kern<WW, 8><<<gW, blk, 0, stream>>>(out, q_u, b_u, h + 1, h);

        transpose_kern<<<dim3(7, 3, 4096), dim3(32, 8), 0, stream>>>(out, ws, HH, WW);

        const dim3 gH(3, 4, 32);    // 384 blocks: 32c x 24l tiles
        for (int w = 1; w < WW; w++)
            step2_kern<HH, 6><<<gH, blk, 0, stream>>>(ws, q_r, b_r, w - 1, w);
        for (int w = WW - 2; w >= 0; w--)
            step2_kern<HH, 6><<<gH, blk, 0, stream>>>(ws, q_l, b_l, w + 1, w);

        transpose_kern<<<dim3(3, 7, 4096), dim3(32, 8), 0, stream>>>(ws, out, WW, HH);
    } else if (ws_size >= bytes) {
        // ---------------- old transposed path (no room for wrep) -----------
        const dim3 gW(7, 2, 32), blk(256);
        for (int h = 1; h < HH; h++)
            step_kern<WW><<<gW, blk, 0, stream>>>(out, w_d, b_d, h - 1, h);
        for (int h = HH - 2; h >= 0; h--)
            step_kern<WW><<<gW, blk, 0, stream>>>(out, w_u, b_u, h + 1, h);

        transpose_kern<<<dim3(7, 3, 4096), dim3(32, 8), 0, stream>>>(out, ws, HH, WW);
        const dim3 gH(3, 2, 32);
        for (int w = 1; w < WW; w++)
            step_kern<HH><<<gH, blk, 0, stream>>>(ws, w_r, b_r, w - 1, w);
        for (int w = WW - 2; w >= 0; w--)
            step_kern<HH><<<gH, blk, 0, stream>>>(ws, w_l, b_l, w + 1, w);
        transpose_kern<<<dim3(3, 7, 4096), dim3(32, 8), 0, stream>>>(ws, out, WW, HH);
    } else {
        // ---------------- last-resort strided fallback ---------------------
        const dim3 gW(7, 2, 32), blk(256);
        for (int h = 1; h < HH; h++)
            step_kern<WW><<<gW, blk, 0, stream>>>(out, w_d, b_d, h - 1, h);
        for (int h = HH - 2; h >= 0; h--)
            step_kern<WW><<<gW, blk, 0, stream>>>(out, w_u, b_u, h + 1, h);
        const dim3 gB(3, 4, 32);
        for (int w = 1; w < WW; w++)
            stepH_kern<<<gB, blk, 0, stream>>>(out, w_r, b_r, w - 1, w);
        for (int w = WW - 2; w >= 0; w--)
            stepH_kern<<<gB, blk, 0, stream>>>(out, w_l, b_l, w + 1, w);
    }
}